// Round 11
// baseline (68.960 us; speedup 1.0000x reference)
//
#include <hip/hip_runtime.h>

// Batched Thomas tridiagonal solve, B=8192 rows, N=4096.
//   a_i = alpha[i-1]^2 (a_0=0); b_i = max(5+alpha[i]^3, 0.01);
//   c_i = alpha[i+1]^2 + 2*alpha[i+1]; rhs f (shared across rows).
//
// Chunked UL elimination with halos. Carry-gain bound: d(ec)/d(ec_prev) =
// a^2*c/dn^2 <= 3/4.3^2 = 0.162 -> right halo H=8 worst-case err 5e-7.
// Subst decay |ep| <= 0.233 -> left halo HL=8 err 8e-6. Thr 2.25e-2.
//
// R11: occupancy experiment. R7-R10 pinned at ~25% (2 waves/SIMD) regardless
// of work content -> resident-parallelism-limited. Same wave structure and
// math as R10, but 4 waves/block (256 thr), launch_bounds(256,4), LDS 38.5KB
// -> 4 blocks/CU = 16 waves/CU (50% cap; R3/R4 family measured 38-39%).

namespace {
constexpr int kN   = 4096;
constexpr int kCH  = 32;              // outputs per lane
constexpr int kHL  = 8;               // left halo
constexpr int kR   = kCH + kHL;       // stored region = 40 (groups 0..9)
constexpr int kNC  = kN / kCH;        // 128 chunks per row
constexpr int RPW  = 8;               // rows per wave
constexpr int WAVES = 4;
constexpr int THREADS = 64 * WAVES;   // 256
constexpr int F4PR = 69;              // staged f4/row: cols [cb-12, cb+264)
constexpr int ST4  = 71;              // A row stride in f4 (284 dw; %32==28)
constexpr int APW4 = RPW * ST4;       // 568 f4 per wave A panel
constexpr int SF4  = 133;             // shared f pair window (idx 0..132)
constexpr int GHI  = 11;              // top group (halo groups 10..11)
}

__global__ __launch_bounds__(THREADS, 4) void thomas_v11(
    const float4* __restrict__ alpha4,
    const float4* __restrict__ f4,
    float4* __restrict__ u4)
{
  __shared__ float4 sM[WAVES * APW4 + SF4];   // 2405 f4 = 38480 B

  const int bid  = blockIdx.x;
  const int pair = bid & 7;                     // 512-col window pair
  const int r0   = (bid >> 3) * (WAVES * RPW);  // 32 rows per block
  const int w    = threadIdx.x >> 6;
  const int lane = threadIdx.x & 63;
  const int rw0  = r0 + w * RPW;
  const int j    = lane & 7;                    // row-local (quarter-wave: 8 rows)
  const int q    = lane >> 3;                   // chunk-local 0..7

  float4* __restrict__ sA = sM + w * APW4;      // wave-private [RPW][ST4]
  float4* __restrict__ sF = sM + WAVES * APW4;  // block-shared f pair window

#define LOAD_TILE(cw, P)                                              \
  {                                                                   \
    const int cb4 = (cw) * 64 - 3;                                    \
    _Pragma("unroll")                                                 \
    for (int it = 0; it < 9; ++it) {                                  \
      int idx = lane + it * 64;                                       \
      if (idx > RPW * F4PR - 1) idx = RPW * F4PR - 1;  /* dup */      \
      const int row = idx / F4PR;                                     \
      const int c4  = idx - row * F4PR;                               \
      int g4 = cb4 + c4;                                              \
      g4 = (g4 < 0) ? 0 : ((g4 > 1023) ? 1023 : g4);  /* dups unused */ \
      P[it] = alpha4[(size_t)(rw0 + row) * 1024 + g4];                \
    }                                                                 \
  }

#define WRITE_TILE(P)                                                 \
  {                                                                   \
    _Pragma("unroll")                                                 \
    for (int it = 0; it < 9; ++it) {                                  \
      const int idx = lane + it * 64;                                 \
      if (idx < RPW * F4PR) {                                         \
        const int row = idx / F4PR;                                   \
        const int c4  = idx - row * F4PR;                             \
        sA[row * ST4 + c4] = P[it];                                   \
      }                                                               \
    }                                                                 \
  }

#define STEP(am1v, fiv)                                        \
  {                                                            \
    const float c_  = ap1 * (ap1 + 2.0f);                      \
    const float b_  = fmaxf(fmaf(a0 * a0, a0, 5.0f), 0.01f);   \
    const float dn  = fmaf(-c_, ec, b_);                       \
    const float rd  = __builtin_amdgcn_rcpf(dn);               \
    gc = (fiv - c_ * gc) * rd;                                 \
    ec = ((am1v) * (am1v)) * rd;                               \
    ap1 = a0; a0 = (am1v);                                     \
  }

  // Solve one tile from sA/sF; CWL is a compile-time 0/1.
#define SOLVE_TILE(CWL)                                                   \
  {                                                                       \
    const int  kk    = (pair * 2 + (CWL)) * 8 + q;                        \
    const bool first = (kk == 0);                                         \
    const bool last  = (kk == kNC - 1);                                   \
    const int  f4b   = first ? 3 : (q * 8 + 1);                           \
    const int  fOff  = (CWL) * 64;                                        \
    const float4* __restrict__ A4 = sA + j * ST4;                         \
    float gp[kR], ep[kR];                                                 \
    float ec = 0.0f, gc = 0.0f, ap1 = 0.0f;                               \
    const int ghi = last ? 9 : GHI;                                       \
    float4 curA = A4[f4b + ghi];                                          \
    float4 lowA = A4[f4b + ghi - 1];                                      \
    float4 fcur = sF[fOff + f4b + ghi];                                   \
    float4 flow = sF[fOff + f4b + ghi - 1];                               \
    float a0 = curA.w;                                                    \
    if (!last) {                                                          \
      _Pragma("unroll")                                                   \
      for (int g = GHI; g >= 10; --g) {                                   \
        const float4 pA = A4[f4b + g - 2];                                \
        const float4 pF = sF[fOff + f4b + g - 2];                         \
        STEP(curA.z, fcur.w)                                              \
        STEP(curA.y, fcur.z)                                              \
        STEP(curA.x, fcur.y)                                              \
        STEP(lowA.w, fcur.x)                                              \
        curA = lowA; lowA = pA; fcur = flow; flow = pF;                   \
      }                                                                   \
    }                                                                     \
    _Pragma("unroll")                                                     \
    for (int g = 9; g >= 0; --g) {                                        \
      int pidx = f4b + g - 2;                                             \
      if (pidx < 0) pidx = 0;            /* value unused when clamped */  \
      const float4 pA = A4[pidx];                                         \
      const float4 pF = sF[fOff + pidx];                                  \
      float lw = lowA.w;                                                  \
      if (g == 0 && first) lw = 0.0f;    /* a_0 = 0 */                    \
      STEP(curA.z, fcur.w)  gp[4*g+3] = gc; ep[4*g+3] = ec;               \
      STEP(curA.y, fcur.z)  gp[4*g+2] = gc; ep[4*g+2] = ec;               \
      STEP(curA.x, fcur.y)  gp[4*g+1] = gc; ep[4*g+1] = ec;               \
      STEP(lw,     fcur.x)  gp[4*g+0] = gc; ep[4*g+0] = ec;               \
      curA = lowA; lowA = pA; fcur = flow; flow = pF;                     \
    }                                                                     \
    const int tmin = first ? 0 : kHL;                                     \
    float up = 0.0f;                                                      \
    float4 pk;                                                            \
    _Pragma("unroll")                                                     \
    for (int t = 0; t < kR; ++t) {                                        \
      const float uv = fmaf(-ep[t], up, gp[t]);                           \
      up = uv;                                                            \
      const int ph = t & 3;                                               \
      if      (ph == 0) pk.x = uv;                                        \
      else if (ph == 1) pk.y = uv;                                        \
      else if (ph == 2) pk.z = uv;                                        \
      else {                                                              \
        pk.w = uv;                                                        \
        if (t - 3 >= tmin && t < tmin + kCH) {                            \
          sA[j * ST4 + q * 8 + ((t - 3 - tmin) >> 2)] = pk;               \
        }                                                                 \
      }                                                                   \
    }                                                                     \
    _Pragma("unroll")                                                     \
    for (int it = 0; it < RPW; ++it) {                                    \
      const float4 v = sA[it * ST4 + lane];                               \
      u4[(size_t)(rw0 + it) * 1024 + (pair * 2 + (CWL)) * 64 + lane] = v; \
    }                                                                     \
  }

  // ---- shared f window (idempotent writes by all waves; no barrier) ----
  {
    const int fb4 = pair * 128 - 3;
    #pragma unroll
    for (int it = 0; it < 3; ++it) {
      const int idx = lane + it * 64;
      if (idx < SF4) {
        int g4 = fb4 + idx;
        g4 = (g4 < 0) ? 0 : ((g4 > 1023) ? 1023 : g4);
        sF[idx] = f4[g4];
      }
    }
  }

  // ---- two-tile pipeline with pinned prefetch ----
  float4 p0[9];
  LOAD_TILE(pair * 2, p0)
  WRITE_TILE(p0)

  float4 p1[9];
  LOAD_TILE(pair * 2 + 1, p1)   // issued BEFORE T0 compute
  asm volatile("" ::: "memory"); // anti-sink fence

  SOLVE_TILE(0)                 // compute + subst + dump T0

  WRITE_TILE(p1)                // vmcnt wait for p1 lands here

  SOLVE_TILE(1)

#undef LOAD_TILE
#undef WRITE_TILE
#undef STEP
#undef SOLVE_TILE
}

extern "C" void kernel_launch(void* const* d_in, const int* in_sizes, int n_in,
                              void* d_out, int out_size, void* d_ws, size_t ws_size,
                              hipStream_t stream) {
  const float4* alpha = (const float4*)d_in[0];
  const float4* f     = (const float4*)d_in[1];
  float4*       uo    = (float4*)d_out;
  // grid: 256 row-groups (32 rows) x 8 window-pairs (512 cols) = 2048 blocks
  thomas_v11<<<dim3(2048), THREADS, 0, stream>>>(alpha, f, uo);
}

// Round 13
// 49.539 us; speedup vs baseline: 1.3920x; 1.3920x over previous
//
#include <hip/hip_runtime.h>

// Batched Thomas tridiagonal solve, B=8192 rows, N=4096.
//   a_i = alpha[i-1]^2 (a_0=0); b_i = max(5+alpha[i]^3, 0.01);
//   c_i = alpha[i+1]^2 + 2*alpha[i+1]; rhs f (shared across rows).
//
// Chunked UL elimination with halos. Carry-gain bound: d(ec)/d(ec_prev) =
// a^2*c/dn^2 <= 3/4.3^2 = 0.162 -> right halo H=8 worst-case err 5e-7.
// Subst decay |ep| <= 0.233 -> left halo HL=8 err 8e-6. Thr 2.25e-2.
//
// R13: R12 retry — __builtin_nontemporal_store needs a native vector type,
// not HIP_vector_type. Cast through ext_vector_type(4) float. Theory: u is
// write-once never-read; nt (evict-first) stores stop u's 134 MB stream from
// evicting alpha (134 MB) out of the 256 MB L3 across replays -> HBM reads
// collapse. Everything else identical to R10 (absmax anchor 0.0078125).

namespace {
constexpr int kN   = 4096;
constexpr int kCH  = 32;              // outputs per lane
constexpr int kHL  = 8;               // left halo
constexpr int kR   = kCH + kHL;       // stored region = 40 (groups 0..9)
constexpr int kNC  = kN / kCH;        // 128 chunks per row
constexpr int RPW  = 8;               // rows per wave
constexpr int WAVES = 2;
constexpr int THREADS = 64 * WAVES;   // 128
constexpr int F4PR = 69;              // staged f4/row: cols [cb-12, cb+264)
constexpr int ST4  = 71;              // A row stride in f4 (284 dw; %32==28)
constexpr int APW4 = RPW * ST4;       // 568 f4 per wave A panel
constexpr int SF4  = 133;             // shared f pair window (idx 0..132)
constexpr int GHI  = 11;              // top group (halo groups 10..11)
}

using f4v = float __attribute__((ext_vector_type(4)));

__global__ __launch_bounds__(THREADS, 3) void thomas_v13(
    const float4* __restrict__ alpha4,
    const float4* __restrict__ f4,
    float4* __restrict__ u4)
{
  __shared__ float4 sM[WAVES * APW4 + SF4];   // 1269 f4 = 20304 B

  const int bid  = blockIdx.x;
  const int pair = bid & 7;                     // 512-col window pair
  const int r0   = (bid >> 3) * (WAVES * RPW);
  const int w    = threadIdx.x >> 6;
  const int lane = threadIdx.x & 63;
  const int rw0  = r0 + w * RPW;
  const int j    = lane & 7;                    // row-local (quarter-wave: 8 rows)
  const int q    = lane >> 3;                   // chunk-local 0..7

  float4* __restrict__ sA = sM + w * APW4;      // wave-private [RPW][ST4]
  float4* __restrict__ sF = sM + WAVES * APW4;  // block-shared f pair window

#define LOAD_TILE(cw, P)                                              \
  {                                                                   \
    const int cb4 = (cw) * 64 - 3;                                    \
    _Pragma("unroll")                                                 \
    for (int it = 0; it < 9; ++it) {                                  \
      int idx = lane + it * 64;                                       \
      if (idx > RPW * F4PR - 1) idx = RPW * F4PR - 1;  /* dup */      \
      const int row = idx / F4PR;                                     \
      const int c4  = idx - row * F4PR;                               \
      int g4 = cb4 + c4;                                              \
      g4 = (g4 < 0) ? 0 : ((g4 > 1023) ? 1023 : g4);  /* dups unused */ \
      P[it] = alpha4[(size_t)(rw0 + row) * 1024 + g4];                \
    }                                                                 \
  }

#define WRITE_TILE(P)                                                 \
  {                                                                   \
    _Pragma("unroll")                                                 \
    for (int it = 0; it < 9; ++it) {                                  \
      const int idx = lane + it * 64;                                 \
      if (idx < RPW * F4PR) {                                         \
        const int row = idx / F4PR;                                   \
        const int c4  = idx - row * F4PR;                             \
        sA[row * ST4 + c4] = P[it];                                   \
      }                                                               \
    }                                                                 \
  }

#define STEP(am1v, fiv)                                        \
  {                                                            \
    const float c_  = ap1 * (ap1 + 2.0f);                      \
    const float b_  = fmaxf(fmaf(a0 * a0, a0, 5.0f), 0.01f);   \
    const float dn  = fmaf(-c_, ec, b_);                       \
    const float rd  = __builtin_amdgcn_rcpf(dn);               \
    gc = (fiv - c_ * gc) * rd;                                 \
    ec = ((am1v) * (am1v)) * rd;                               \
    ap1 = a0; a0 = (am1v);                                     \
  }

  // Solve one tile from sA/sF; CWL is a compile-time 0/1.
#define SOLVE_TILE(CWL)                                                   \
  {                                                                       \
    const int  kk    = (pair * 2 + (CWL)) * 8 + q;                        \
    const bool first = (kk == 0);                                         \
    const bool last  = (kk == kNC - 1);                                   \
    const int  f4b   = first ? 3 : (q * 8 + 1);                           \
    const int  fOff  = (CWL) * 64;                                        \
    const float4* __restrict__ A4 = sA + j * ST4;                         \
    float gp[kR], ep[kR];                                                 \
    float ec = 0.0f, gc = 0.0f, ap1 = 0.0f;                               \
    const int ghi = last ? 9 : GHI;                                       \
    float4 curA = A4[f4b + ghi];                                          \
    float4 lowA = A4[f4b + ghi - 1];                                      \
    float4 fcur = sF[fOff + f4b + ghi];                                   \
    float4 flow = sF[fOff + f4b + ghi - 1];                               \
    float a0 = curA.w;                                                    \
    if (!last) {                                                          \
      _Pragma("unroll")                                                   \
      for (int g = GHI; g >= 10; --g) {                                   \
        const float4 pA = A4[f4b + g - 2];                                \
        const float4 pF = sF[fOff + f4b + g - 2];                         \
        STEP(curA.z, fcur.w)                                              \
        STEP(curA.y, fcur.z)                                              \
        STEP(curA.x, fcur.y)                                              \
        STEP(lowA.w, fcur.x)                                              \
        curA = lowA; lowA = pA; fcur = flow; flow = pF;                   \
      }                                                                   \
    }                                                                     \
    _Pragma("unroll")                                                     \
    for (int g = 9; g >= 0; --g) {                                        \
      int pidx = f4b + g - 2;                                             \
      if (pidx < 0) pidx = 0;            /* value unused when clamped */  \
      const float4 pA = A4[pidx];                                         \
      const float4 pF = sF[fOff + pidx];                                  \
      float lw = lowA.w;                                                  \
      if (g == 0 && first) lw = 0.0f;    /* a_0 = 0 */                    \
      STEP(curA.z, fcur.w)  gp[4*g+3] = gc; ep[4*g+3] = ec;               \
      STEP(curA.y, fcur.z)  gp[4*g+2] = gc; ep[4*g+2] = ec;               \
      STEP(curA.x, fcur.y)  gp[4*g+1] = gc; ep[4*g+1] = ec;               \
      STEP(lw,     fcur.x)  gp[4*g+0] = gc; ep[4*g+0] = ec;               \
      curA = lowA; lowA = pA; fcur = flow; flow = pF;                     \
    }                                                                     \
    const int tmin = first ? 0 : kHL;                                     \
    float up = 0.0f;                                                      \
    float4 pk;                                                            \
    _Pragma("unroll")                                                     \
    for (int t = 0; t < kR; ++t) {                                        \
      const float uv = fmaf(-ep[t], up, gp[t]);                           \
      up = uv;                                                            \
      const int ph = t & 3;                                               \
      if      (ph == 0) pk.x = uv;                                        \
      else if (ph == 1) pk.y = uv;                                        \
      else if (ph == 2) pk.z = uv;                                        \
      else {                                                              \
        pk.w = uv;                                                        \
        if (t - 3 >= tmin && t < tmin + kCH) {                            \
          sA[j * ST4 + q * 8 + ((t - 3 - tmin) >> 2)] = pk;               \
        }                                                                 \
      }                                                                   \
    }                                                                     \
    _Pragma("unroll")                                                     \
    for (int it = 0; it < RPW; ++it) {                                    \
      const float4 v = sA[it * ST4 + lane];                               \
      f4v vv; vv.x = v.x; vv.y = v.y; vv.z = v.z; vv.w = v.w;             \
      __builtin_nontemporal_store(vv, reinterpret_cast<f4v*>(             \
          u4 + (size_t)(rw0 + it) * 1024 + (pair * 2 + (CWL)) * 64 + lane)); \
    }                                                                     \
  }

  // ---- shared f window (idempotent writes by both waves; no barrier) ----
  {
    const int fb4 = pair * 128 - 3;
    #pragma unroll
    for (int it = 0; it < 3; ++it) {
      const int idx = lane + it * 64;
      if (idx < SF4) {
        int g4 = fb4 + idx;
        g4 = (g4 < 0) ? 0 : ((g4 > 1023) ? 1023 : g4);
        sF[idx] = f4[g4];
      }
    }
  }

  // ---- two-tile pipeline with pinned prefetch ----
  float4 p0[9];
  LOAD_TILE(pair * 2, p0)
  WRITE_TILE(p0)

  float4 p1[9];
  LOAD_TILE(pair * 2 + 1, p1)   // issued BEFORE T0 compute
  asm volatile("" ::: "memory"); // anti-sink fence

  SOLVE_TILE(0)                 // compute + subst + dump T0

  WRITE_TILE(p1)                // vmcnt wait for p1 lands here

  SOLVE_TILE(1)

#undef LOAD_TILE
#undef WRITE_TILE
#undef STEP
#undef SOLVE_TILE
}

extern "C" void kernel_launch(void* const* d_in, const int* in_sizes, int n_in,
                              void* d_out, int out_size, void* d_ws, size_t ws_size,
                              hipStream_t stream) {
  const float4* alpha = (const float4*)d_in[0];
  const float4* f     = (const float4*)d_in[1];
  float4*       uo    = (float4*)d_out;
  // grid: 512 row-groups (16 rows) x 8 window-pairs (512 cols) = 4096 blocks
  thomas_v13<<<dim3(4096), THREADS, 0, stream>>>(alpha, f, uo);
}